// Round 14
// baseline (165.955 us; speedup 1.0000x reference)
//
#include <hip/hip_runtime.h>
#include <hip/hip_bf16.h>

using bf16 = __hip_bfloat16;

typedef __attribute__((ext_vector_type(8))) short bf16x8_t;
typedef __attribute__((ext_vector_type(4))) float f32x4_t;

__device__ __forceinline__ float b2f(bf16 x){ return __bfloat162float(x); }
__device__ __forceinline__ bf16  f2b(float x){ return __float2bfloat16(x); }
__device__ __forceinline__ unsigned short f2bu(float x){ bf16 h = __float2bfloat16(x); return *(unsigned short*)&h; }
__device__ __forceinline__ float bits2f(unsigned int lo16){ return __uint_as_float(lo16 << 16); }

__device__ __forceinline__ void gload16(const void* g, void* l) {
    __builtin_amdgcn_global_load_lds(
        (const __attribute__((address_space(1))) unsigned int*)g,
        (__attribute__((address_space(3))) unsigned int*)l, 16, 0, 0);
}

// ---------------------------------------------------------------------------
// Dims: B=16, C=256, H=W=32, N=1024, padded P=34x34=1156, Cq=32
// conv/pv: 128x128 tile, 256 thr (4 waves, 2x2), wave tile 64x64 (32.8
// FLOP/LDS-byte vs 21.8 at 64x32 — LDS-read-bound fix), counted vmcnt.
// conv A: halo-slab (staged once per 64-ch chunk). bn_apply separate (r11).
// ---------------------------------------------------------------------------

// ---- mega-prep: [0,1024) prep_x | [1024,1792) conv-w | [1792,2112) qkv-w |
//      [2112,2128) time_mlp | [2128,3184) halo-zero (Xp0+Xp1) ----
__global__ __launch_bounds__(256) void prep_all_k(
    const float* __restrict__ x, bf16* __restrict__ Xp0, bf16* __restrict__ Xp1,
    float* __restrict__ sums,
    const float* __restrict__ t, const float* __restrict__ w_t1, const float* __restrict__ b_t1,
    const float* __restrict__ w_t2, const float* __restrict__ b_t2, float* __restrict__ te,
    const float* __restrict__ w1, const float* __restrict__ w2, const float* __restrict__ w3,
    bf16* __restrict__ W1, bf16* __restrict__ W2, bf16* __restrict__ W3o,
    const float* __restrict__ wq, const float* __restrict__ wk, const float* __restrict__ wv,
    bf16* __restrict__ WQK, bf16* __restrict__ WVb)
{
    __shared__ char smem[64 * 65 * 4];
    const int blk = blockIdx.x;
    const int tid = threadIdx.x;

    if (blk < 1024) {
        float (*xs)[65] = (float(*)[65])smem;
        if (blk == 0) {
            sums[tid] = 0.f; sums[tid + 256] = 0.f; sums[tid + 512] = 0.f; sums[tid + 768] = 0.f;
        }
        const int b = blk >> 6, ct = (blk >> 4) & 3, nt = blk & 15;
        const int c0 = ct << 6, n0 = nt << 6;
        {
            const int cl = tid >> 2, nc = (tid & 3) << 4;
            const float* src = x + (size_t)((b << 8) + c0 + cl) * 1024 + n0 + nc;
            #pragma unroll
            for (int j = 0; j < 16; j += 4) {
                const float4 v = *(const float4*)(src + j);
                xs[cl][nc + j] = v.x; xs[cl][nc + j + 1] = v.y;
                xs[cl][nc + j + 2] = v.z; xs[cl][nc + j + 3] = v.w;
            }
        }
        __syncthreads();
        {
            const int nl = tid >> 2, cc = (tid & 3) << 4;
            const int n = n0 + nl;
            const int p = ((n >> 5) + 1) * 34 + (n & 31) + 1;
            unsigned int u[8];
            #pragma unroll
            for (int k = 0; k < 8; ++k)
                u[k] = (unsigned int)f2bu(xs[cc + 2 * k][nl]) | ((unsigned int)f2bu(xs[cc + 2 * k + 1][nl]) << 16);
            bf16* dst = Xp0 + (size_t)(b * 1156 + p) * 256 + c0 + cc;
            *(uint4*)dst = make_uint4(u[0], u[1], u[2], u[3]);
            *(uint4*)(dst + 8) = make_uint4(u[4], u[5], u[6], u[7]);
        }
    } else if (blk < 1792) {
        float* ls = (float*)smem;
        const int id = blk - 1024;
        const int co = id & 255;
        const int sel = id >> 8;
        const float* w = (sel == 0) ? w1 : (sel == 1) ? w2 : w3;
        bf16* dst = (sel == 0) ? W1 : (sel == 1) ? W2 : W3o;
        const float* src = w + (size_t)co * 2304;
        #pragma unroll
        for (int i = 0; i < 9; ++i) ls[tid + (i << 8)] = src[tid + (i << 8)];
        __syncthreads();
        #pragma unroll
        for (int off = 0; off < 9; ++off)
            dst[(size_t)(co * 9 + off) * 256 + tid] = f2b(ls[tid * 9 + off]);
    } else if (blk < 2112) {
        const int r = blk - 1792;
        if (r < 32)       WQK[r * 256 + tid] = f2b(wq[r * 256 + tid]);
        else if (r < 64)  WQK[r * 256 + tid] = f2b(wk[(r - 32) * 256 + tid]);
        else              WVb[(r - 64) * 256 + tid] = f2b(wv[(r - 64) * 256 + tid]);
    } else if (blk < 2128) {
        float* tr = (float*)smem;
        float* hid = tr + 256;
        const int b = blk - 2112, j = tid;
        tr[j] = t[(b << 8) + j];
        __syncthreads();
        float s = b_t1[j];
        const float* wp = w_t1 + j * 256;
        for (int k = 0; k < 256; ++k) s += tr[k] * wp[k];
        hid[j] = fmaxf(s, 0.f);
        __syncthreads();
        float s2 = b_t2[j];
        const float* wp2 = w_t2 + j * 256;
        for (int k = 0; k < 256; ++k) s2 += hid[k] * wp2[k];
        te[(b << 8) + j] = fmaxf(s2, 0.f);
    } else {
        const int idx = (blk - 2128) * 256 + tid;
        const int v = idx >> 6;
        const int o = (idx & 63) << 1;
        if (v < 4224) {
            const int buf = v / 2112;
            const int rem = v - buf * 2112;
            const int b = rem / 132;
            const int h = rem - b * 132;
            int p;
            if (h < 34)        p = h;
            else if (h < 68)   p = 1122 + (h - 34);
            else if (h < 100)  p = (h - 68 + 1) * 34;
            else               p = (h - 100 + 1) * 34 + 33;
            unsigned int* dst = (unsigned int*)((buf ? Xp1 : Xp0) + (size_t)(b * 1156 + p) * 256);
            dst[o] = 0u; dst[o + 1] = 0u;
        }
    }
}

// ---- conv3x3 halo-slab implicit GEMM: 128x128 tile, 256 thr, 4 waves ----
// Wave tile 64x64 (2x2 wave grid). A slab dbuf (2x32KB), B 3-buf (3x16KB).
// vmcnt ledger: A stage=8 loads, B stage=4. off==8 -> 12, else 4.
template<bool RELU, bool STATS>
__global__ __launch_bounds__(256, 1) void conv_mfma_k(
    const bf16* __restrict__ Xp, const bf16* __restrict__ W3,
    const float* __restrict__ bias, bf16* __restrict__ outp, float* __restrict__ sums)
{
    __shared__ bf16 Als[2][16384];
    __shared__ bf16 Bls[3][8192];
    __shared__ float sstat[256];
    const int tid = threadIdx.x;
    const int wid = tid >> 6, lane = tid & 63;
    const int wm = wid >> 1, wn = wid & 1;
    const int blk = blockIdx.x;
    const int xc = blk & 7, tt = blk >> 3;
    const int b = xc + ((tt >> 4) << 3);
    const int tile = tt & 15, mt = tile >> 1, nt = tile & 1;
    const int m0 = mt << 7, co0 = nt << 7;

    if (STATS) sstat[tid] = 0.f;

    const bf16* xsl = Xp + (size_t)(b * 1156 + mt * 136) * 256;

    // A slab staging: 8 gload16/thread per cic
    const int l8 = lane >> 3;
    const int aj = ((lane & 7) ^ l8) << 3;
    const bf16* agp[8];
    #pragma unroll
    for (int i = 0; i < 8; ++i)
        agp[i] = xsl + (size_t)((i << 5) + (wid << 3) + l8) * 256 + aj;

    // B staging: 4 gload16/thread per step
    const int brr = tid >> 3;                       // 0..31
    const int sL8 = (((tid & 7) ^ (brr & 7)) << 3);
    const bf16* bgp[4];
    #pragma unroll
    for (int i = 0; i < 4; ++i)
        bgp[i] = W3 + (size_t)(co0 + (i << 5) + brr) * 2304 + sL8;

    const int rsel = lane & 15, lg = lane >> 4;
    const int s0 = ((lg ^ (lane & 7)) << 3);
    const int s1 = (((lg + 4) ^ (lane & 7)) << 3);
    const int bbase = ((wn << 6) + rsel) << 6;
    int dbase[4];
    #pragma unroll
    for (int mi = 0; mi < 4; ++mi)
        dbase[mi] = ((wm << 1) + (mi >> 1)) * 34 + ((mi & 1) << 4) + rsel;

    f32x4_t acc[4][4];
    #pragma unroll
    for (int mi = 0; mi < 4; ++mi)
        #pragma unroll
        for (int ni = 0; ni < 4; ++ni)
            acc[mi][ni] = (f32x4_t){0.f, 0.f, 0.f, 0.f};

    auto STAGE_A = [&](int cic, int buf) {
        #pragma unroll
        for (int i = 0; i < 8; ++i)
            gload16(agp[i] + (cic << 6), &Als[buf][(i << 11) + (wid << 9)]);
    };
    auto STAGE_B = [&](int st, int buf) {
        const int koff = ((st % 9) << 8) + ((st / 9) << 6);
        #pragma unroll
        for (int i = 0; i < 4; ++i)
            gload16(bgp[i] + koff, &Bls[buf][(i << 11) + (wid << 9)]);
    };

    STAGE_A(0, 0);
    STAGE_B(0, 0);
    STAGE_B(1, 1);

    #pragma unroll
    for (int st = 0; st < 36; ++st) {
        if (st == 35)           asm volatile("s_waitcnt vmcnt(0)" ::: "memory");
        else if (st % 9 == 8)   asm volatile("s_waitcnt vmcnt(12)" ::: "memory");
        else                    asm volatile("s_waitcnt vmcnt(4)" ::: "memory");
        __builtin_amdgcn_s_barrier();
        asm volatile("" ::: "memory");
        const int cic = st / 9, off = st % 9;
        const int doff = (off / 3) * 34 + (off % 3);
        const bf16* abuf = Als[cic & 1];
        const bf16* bbuf = Bls[st % 3];
        #pragma unroll
        for (int kh = 0; kh < 2; ++kh) {
            const int sk = kh ? s1 : s0;
            bf16x8_t av[4], bv[4];
            #pragma unroll
            for (int mi = 0; mi < 4; ++mi) {
                const int sp = dbase[mi] + doff;
                av[mi] = *(const bf16x8_t*)((const char*)abuf +
                            (sp << 7) + ((((kh << 2) + lg) ^ (sp & 7)) << 4));
            }
            #pragma unroll
            for (int ni = 0; ni < 4; ++ni)
                bv[ni] = *(const bf16x8_t*)(bbuf + bbase + (ni << 10) + sk);
            #pragma unroll
            for (int mi = 0; mi < 4; ++mi)
                #pragma unroll
                for (int ni = 0; ni < 4; ++ni)
                    acc[mi][ni] = __builtin_amdgcn_mfma_f32_16x16x32_bf16(
                        av[mi], bv[ni], acc[mi][ni], 0, 0, 0);
        }
        if (st + 2 < 36) STAGE_B(st + 2, (st + 2) % 3);
        if (off == 7 && st < 27) STAGE_A(cic + 1, (cic + 1) & 1);
    }

    const int cr = lg << 2;
    const int cc = rsel;
    #pragma unroll
    for (int ni = 0; ni < 4; ++ni) {
        const int co = co0 + (wn << 6) + (ni << 4) + cc;
        const float bb = bias[co];
        float ssum = 0.f, ssq = 0.f;
        #pragma unroll
        for (int mi = 0; mi < 4; ++mi) {
            const int nb = m0 + (wm << 6) + (mi << 4) + cr;
            #pragma unroll
            for (int j = 0; j < 4; ++j) {
                float v = acc[mi][ni][j] + bb;
                if (RELU) v = fmaxf(v, 0.f);
                outp[(size_t)((b << 10) + nb + j) * 256 + co] = f2b(v);
                if (STATS) { ssum += v; ssq += v * v; }
            }
        }
        if (STATS) {
            ssum += __shfl_xor(ssum, 16); ssum += __shfl_xor(ssum, 32);
            ssq  += __shfl_xor(ssq, 16);  ssq  += __shfl_xor(ssq, 32);
            if (lane < 16) {
                const int ch = (wn << 6) + (ni << 4) + cc;   // 0..127
                atomicAdd(&sstat[ch * 2], ssum);
                atomicAdd(&sstat[ch * 2 + 1], ssq);
            }
        }
    }
    if (STATS) {
        __syncthreads();
        if (tid < 128) {
            atomicAdd(&sums[co0 + tid], sstat[tid * 2]);
            atomicAdd(&sums[256 + co0 + tid], sstat[tid * 2 + 1]);
        }
    }
}

// bn apply; computes scale/shift from sums locally; writes padded Xp interior
template<bool TE>
__global__ __launch_bounds__(256) void bn_apply_T_k(
    const bf16* __restrict__ a, const float* __restrict__ sums,
    const float* __restrict__ g, const float* __restrict__ bb,
    const float* __restrict__ te, bf16* __restrict__ Xp)
{
    const int t = threadIdx.x;
    const int row = blockIdx.x * 8 + (t >> 5);
    const int c0 = (t & 31) << 3;
    const int b = row >> 10, n = row & 1023;
    const uint4 u = *(const uint4*)(a + (size_t)row * 256 + c0);
    const unsigned int w[4] = {u.x, u.y, u.z, u.w};
    float scv[8], shv[8];
    #pragma unroll
    for (int k = 0; k < 8; ++k) {
        const int c = c0 + k;
        const float m = sums[c] * (1.f / 16384.f);
        const float var = sums[256 + c] * (1.f / 16384.f) - m * m;
        const float sc = g[c] * rsqrtf(var + 1e-5f);
        scv[k] = sc;
        shv[k] = bb[c] - m * sc + (TE ? te[(b << 8) + c] : 0.f);
    }
    unsigned int o[4];
    #pragma unroll
    for (int k = 0; k < 4; ++k) {
        const float v0 = bits2f(w[k] & 0xffffu) * scv[2*k] + shv[2*k];
        const float v1 = __uint_as_float(w[k] & 0xffff0000u) * scv[2*k+1] + shv[2*k+1];
        o[k] = (unsigned int)f2bu(v0) | ((unsigned int)f2bu(v1) << 16);
    }
    const int p = ((n >> 5) + 1) * 34 + (n & 31) + 1;
    *(uint4*)(Xp + (size_t)(b * 1156 + p) * 256 + c0) = make_uint4(o[0], o[1], o[2], o[3]);
}

// ---- merged Q|K + V projections (block-range dispatch, 512 thr) ----
__global__ __launch_bounds__(512, 1) void qkv_mfma_k(
    const bf16* __restrict__ WVb, const bf16* __restrict__ Yt,
    const float* __restrict__ bvp, bf16* __restrict__ Vb,
    const bf16* __restrict__ WQK, const float* __restrict__ bq,
    const float* __restrict__ bk, bf16* __restrict__ QKb)
{
    __shared__ bf16 Als[3][128 * 64];
    __shared__ bf16 Bls[3][128 * 64];
    const int tid = threadIdx.x;
    const int wid = tid >> 6, lane = tid & 63;

    if (blockIdx.x >= 256) {
        const int blk2 = blockIdx.x - 256;
        const int b = blk2 >> 3, m0 = (blk2 & 7) << 7;
        const int n0w = m0 + (wid << 4);
        const bf16* arow = Yt + (size_t)((b << 10) + n0w + (lane & 15)) * 256 + ((lane >> 4) << 3);
        const int boff = ((lane >> 4) << 3);
        f32x4_t acc[4];
        #pragma unroll
        for (int ni = 0; ni < 4; ++ni) acc[ni] = (f32x4_t){0.f,0.f,0.f,0.f};
        for (int k0 = 0; k0 < 256; k0 += 32) {
            const bf16x8_t av = *(const bf16x8_t*)(arow + k0);
            #pragma unroll
            for (int ni = 0; ni < 4; ++ni) {
                const bf16x8_t bv = *(const bf16x8_t*)(WQK + (ni * 16 + (lane & 15)) * 256 + k0 + boff);
                acc[ni] = __builtin_amdgcn_mfma_f32_16x16x32_bf16(av, bv, acc[ni], 0, 0, 0);
            }
        }
        const int cr = (lane >> 4) << 2, cc = lane & 15;
        #pragma unroll
        for (int ni = 0; ni < 4; ++ni) {
            const int q = ni * 16 + cc;
            const float bias = (q < 32) ? bq[q] : bk[q - 32];
            #pragma unroll
            for (int j = 0; j < 4; ++j) {
                const int n = n0w + cr + j;
                QKb[(size_t)((b << 10) + n) * 64 + q] = f2b(acc[ni][j] + bias);
            }
        }
        return;
    }

    const int wm = wid >> 2, wn = wid & 3;
    const int blk = blockIdx.x;
    const int xc = blk & 7, tt = blk >> 3;
    const int b = xc + ((tt >> 4) << 3);
    const int tile = tt & 15, vt = tile >> 3, nt = tile & 7;
    const int v0 = vt << 7, n0 = nt << 7;

    const int lrow = tid >> 3;
    const int sL8 = (((tid & 7) ^ (lrow & 7)) << 3);
    const bf16* agp[2]; const bf16* bgp[2];
    #pragma unroll
    for (int i = 0; i < 2; ++i) {
        const int r = (i << 6) + lrow;
        agp[i] = WVb + (size_t)(v0 + r) * 256 + sL8;
        bgp[i] = Yt + (size_t)((b << 10) + n0 + r) * 256 + sL8;
    }
    const int rsel = lane & 15;
    const int s0 = (((lane >> 4) ^ (lane & 7)) << 3);
    const int s1 = ((((lane >> 4) + 4) ^ (lane & 7)) << 3);
    const int abase = ((wm << 6) + rsel) << 6;
    const int bbase = ((wn << 5) + rsel) << 6;

    f32x4_t acc[4][2];
    #pragma unroll
    for (int mi = 0; mi < 4; ++mi)
        #pragma unroll
        for (int ni = 0; ni < 2; ++ni)
            acc[mi][ni] = (f32x4_t){0.f,0.f,0.f,0.f};

    auto STAGE = [&](int kt2, int buf) {
        const int koff = kt2 << 6;
        #pragma unroll
        for (int i = 0; i < 2; ++i) {
            gload16(agp[i] + koff, &Als[buf][((i << 6) + (wid << 3)) << 6]);
            gload16(bgp[i] + koff, &Bls[buf][((i << 6) + (wid << 3)) << 6]);
        }
    };

    STAGE(0, 0); STAGE(1, 1);
    for (int kt = 0; kt < 4; ++kt) {
        if (kt < 3) asm volatile("s_waitcnt vmcnt(4)" ::: "memory");
        else        asm volatile("s_waitcnt vmcnt(0)" ::: "memory");
        __builtin_amdgcn_s_barrier();
        asm volatile("" ::: "memory");
        const int cur = kt % 3;
        #pragma unroll
        for (int kh = 0; kh < 2; ++kh) {
            const int sk = kh ? s1 : s0;
            bf16x8_t av[4], bv[2];
            #pragma unroll
            for (int mi = 0; mi < 4; ++mi)
                av[mi] = *(const bf16x8_t*)(&Als[cur][abase + (mi << 10) + sk]);
            #pragma unroll
            for (int ni = 0; ni < 2; ++ni)
                bv[ni] = *(const bf16x8_t*)(&Bls[cur][bbase + (ni << 10) + sk]);
            #pragma unroll
            for (int mi = 0; mi < 4; ++mi)
                #pragma unroll
                for (int ni = 0; ni < 2; ++ni)
                    acc[mi][ni] = __builtin_amdgcn_mfma_f32_16x16x32_bf16(
                        av[mi], bv[ni], acc[mi][ni], 0, 0, 0);
        }
        if (kt + 2 < 4) STAGE(kt + 2, (kt + 2) % 3);
    }

    const int cr = (lane >> 4) << 2, cc = lane & 15;
    #pragma unroll
    for (int mi = 0; mi < 4; ++mi) {
        #pragma unroll
        for (int j = 0; j < 4; ++j) {
            const int v = v0 + (wm << 6) + (mi << 4) + cr + j;
            const float bb = bvp[v];
            #pragma unroll
            for (int ni = 0; ni < 2; ++ni) {
                const int n = n0 + (wn << 5) + (ni << 4) + cc;
                Vb[(size_t)((b << 8) + v) * 1024 + n] = f2b(acc[mi][ni][j] + bb);
            }
        }
    }
}

// scores + softmax (unnormalized P, deferred 1/sum)
__global__ __launch_bounds__(256) void softmax_k(
    const bf16* __restrict__ QKb, bf16* __restrict__ P, float* __restrict__ invs)
{
    const int b = blockIdx.x >> 5, n0 = (blockIdx.x & 31) << 5;
    const int tid = threadIdx.x, wid = tid >> 6, lane = tid & 63;
    const int m0w = wid << 8;
    __shared__ float wred[4][32];

    const bf16* qbase = QKb + (size_t)((b << 10) + n0) * 64;
    const int koff = (lane >> 4) << 3;
    bf16x8_t qf[2];
    #pragma unroll
    for (int nt = 0; nt < 2; ++nt)
        qf[nt] = *(const bf16x8_t*)(qbase + (nt * 16 + (lane & 15)) * 64 + koff);
    const bf16* kbase = QKb + (size_t)(b << 10) * 64 + 32;

    float mx[2] = {-3.0e38f, -3.0e38f};
    for (int mi = 0; mi < 16; ++mi) {
        const bf16x8_t kf = *(const bf16x8_t*)(kbase + (m0w + mi * 16 + (lane & 15)) * 64 + koff);
        #pragma unroll
        for (int nt = 0; nt < 2; ++nt) {
            f32x4_t s = (f32x4_t){0.f,0.f,0.f,0.f};
            s = __builtin_amdgcn_mfma_f32_16x16x32_bf16(kf, qf[nt], s, 0, 0, 0);
            mx[nt] = fmaxf(mx[nt], fmaxf(fmaxf(s[0], s[1]), fmaxf(s[2], s[3])));
        }
    }
    #pragma unroll
    for (int nt = 0; nt < 2; ++nt) {
        mx[nt] = fmaxf(mx[nt], __shfl_xor(mx[nt], 16));
        mx[nt] = fmaxf(mx[nt], __shfl_xor(mx[nt], 32));
        if (lane < 16) wred[wid][nt * 16 + lane] = mx[nt];
    }
    __syncthreads();
    float rm[2];
    #pragma unroll
    for (int nt = 0; nt < 2; ++nt) {
        const int c = nt * 16 + (lane & 15);
        rm[nt] = fmaxf(fmaxf(wred[0][c], wred[1][c]), fmaxf(wred[2][c], wred[3][c]));
    }
    __syncthreads();

    float sm[2] = {0.f, 0.f};
    for (int mi = 0; mi < 16; ++mi) {
        const bf16x8_t kf = *(const bf16x8_t*)(kbase + (m0w + mi * 16 + (lane & 15)) * 64 + koff);
        #pragma unroll
        for (int nt = 0; nt < 2; ++nt) {
            f32x4_t s = (f32x4_t){0.f,0.f,0.f,0.f};
            s = __builtin_amdgcn_mfma_f32_16x16x32_bf16(kf, qf[nt], s, 0, 0, 0);
            const float p0 = __expf(s[0] - rm[nt]);
            const float p1 = __expf(s[1] - rm[nt]);
            const float p2 = __expf(s[2] - rm[nt]);
            const float p3 = __expf(s[3] - rm[nt]);
            sm[nt] += (p0 + p1) + (p2 + p3);
            uint2 u;
            u.x = (unsigned int)f2bu(p0) | ((unsigned int)f2bu(p1) << 16);
            u.y = (unsigned int)f2bu(p2) | ((unsigned int)f2bu(p3) << 16);
            const int n = n0 + nt * 16 + (lane & 15);
            const int m = m0w + mi * 16 + ((lane >> 4) << 2);
            *(uint2*)(P + (size_t)((b << 10) + n) * 1024 + m) = u;
        }
    }
    #pragma unroll
    for (int nt = 0; nt < 2; ++nt) {
        sm[nt] += __shfl_xor(sm[nt], 16);
        sm[nt] += __shfl_xor(sm[nt], 32);
        if (lane < 16) wred[wid][nt * 16 + lane] = sm[nt];
    }
    __syncthreads();
    if (tid < 32) {
        const float total = wred[0][tid] + wred[1][tid] + wred[2][tid] + wred[3][tid];
        invs[(b << 10) + n0 + tid] = 1.f / total;
    }
}

// PV + residual: 128x128 tile, 256 thr, 4 waves (64x64 wave tile), K=1024.
__global__ __launch_bounds__(256, 1) void pv_mfma_k(
    const bf16* __restrict__ Vb, const bf16* __restrict__ P,
    const float* __restrict__ invs, const bf16* __restrict__ Yt,
    const float* __restrict__ gamma, float* __restrict__ out)
{
    __shared__ bf16 Als[3][8192];
    __shared__ bf16 Bls[3][8192];
    const int tid = threadIdx.x;
    const int wid = tid >> 6, lane = tid & 63;
    const int wm = wid >> 1, wn = wid & 1;
    const int blk = blockIdx.x;
    const int xc = blk & 7, tt = blk >> 3;
    const int b = xc + ((tt >> 4) << 3);
    const int tile = tt & 15, ct = tile >> 3, nt = tile & 7;
    const int c0 = ct << 7, n0 = nt << 7;

    const int brr = tid >> 3;
    const int sL8 = (((tid & 7) ^ (brr & 7)) << 3);
    const bf16* agp[4]; const bf16* bgp[4];
    #pragma unroll
    for (int i = 0; i < 4; ++i) {
        const int r = (i << 5) + brr;
        agp[i] = Vb + (size_t)((b << 8) + c0 + r) * 1024 + sL8;
        bgp[i] = P + (size_t)((b << 10) + n0 + r) * 1024 + sL8;
    }
    const int rsel = lane & 15, lg = lane >> 4;
    const int s0 = ((lg ^ (lane & 7)) << 3);
    const int s1 = (((lg + 4) ^ (lane & 7)) << 3);
    const int abase = ((wm << 6) + rsel) << 6;
    const int bbase = ((wn << 6) + rsel) << 6;

    f32x4_t acc[4][4];
    #pragma unroll
    for (int mi = 0; mi < 4; ++mi)
        #pragma unroll
        for (int ni = 0; ni < 4; ++ni)
            acc[mi][ni] = (f32x4_t){0.f,0.f,0.f,0.f};

    auto STAGE = [&](int kt2, int buf) {
        const int koff = kt2 << 6;
        #pragma unroll
        for (int i = 0; i < 4; ++i) {
            gload16(agp[i] + koff, &Als[buf][(i << 11) + (wid << 9)]);
            gload16(bgp[i] + koff, &Bls[buf][(i << 11) + (wid << 9)]);
        }
    };

    STAGE(0, 0); STAGE(1, 1);
    #pragma unroll
    for (int kt = 0; kt < 16; ++kt) {
        if (kt < 15) asm volatile("s_waitcnt vmcnt(8)" ::: "memory");
        else         asm volatile("s_waitcnt vmcnt(0)" ::: "memory");
        __builtin_amdgcn_s_barrier();
        asm volatile("" ::: "memory");
        const int cur = kt % 3;
        #pragma unroll
        for (int kh = 0; kh < 2; ++kh) {
            const int sk = kh ? s1 : s0;
            bf16x8_t av[4], bv[4];
            #pragma unroll
            for (int mi = 0; mi < 4; ++mi)
                av[mi] = *(const bf16x8_t*)(&Als[cur][abase + (mi << 10) + sk]);
            #pragma unroll
            for (int ni = 0; ni < 4; ++ni)
                bv[ni] = *(const bf16x8_t*)(&Bls[cur][bbase + (ni << 10) + sk]);
            #pragma unroll
            for (int mi = 0; mi < 4; ++mi)
                #pragma unroll
                for (int ni = 0; ni < 4; ++ni)
                    acc[mi][ni] = __builtin_amdgcn_mfma_f32_16x16x32_bf16(
                        av[mi], bv[ni], acc[mi][ni], 0, 0, 0);
        }
        if (kt + 2 < 16) STAGE(kt + 2, (kt + 2) % 3);
    }

    const float g = gamma[0];
    const int cr = lg << 2, cc = rsel;
    #pragma unroll
    for (int ni = 0; ni < 4; ++ni) {
        const int n = n0 + (wn << 6) + (ni << 4) + cc;
        const float gi = g * invs[(b << 10) + n];
        #pragma unroll
        for (int mi = 0; mi < 4; ++mi) {
            const int c = c0 + (wm << 6) + (mi << 4) + cr;
            const bf16* yp = Yt + (size_t)((b << 10) + n) * 256 + c;
            #pragma unroll
            for (int j = 0; j < 4; ++j)
                out[(size_t)((b << 8) + c + j) * 1024 + n] = gi * acc[mi][ni][j] + b2f(yp[j]);
        }
    }
}

// ---------------------------------------------------------------------------
// Workspace (base = ws+32K; round-11 layout):
//  te ws+0 | sums1 ws+16384 | sums2 ws+18432
//  W3_1 [0) W3_2 [1179648) W3_3 [2359296) Xp0 [3538944) Xp1 [13008896)
//  Craw [22478848)  P [0,32M) alias  Yt [33554432) QKb [41943040)
//  Vb [44040192) invs [52428800) WQK [52494336) WVb [52527104)
// ---------------------------------------------------------------------------
extern "C" void kernel_launch(void* const* d_in, const int* in_sizes, int n_in,
                              void* d_out, int out_size, void* d_ws, size_t ws_size,
                              hipStream_t stream)
{
    const float* x     = (const float*)d_in[0];
    const float* t     = (const float*)d_in[1];
    const float* w_t1  = (const float*)d_in[2];
    const float* b_t1  = (const float*)d_in[3];
    const float* w_t2  = (const float*)d_in[4];
    const float* b_t2  = (const float*)d_in[5];
    const float* w_c1  = (const float*)d_in[6];
    const float* b_c1  = (const float*)d_in[7];
    const float* w_c2  = (const float*)d_in[8];
    const float* b_c2  = (const float*)d_in[9];
    const float* w_tr  = (const float*)d_in[10];
    const float* b_tr  = (const float*)d_in[11];
    const float* bn1g  = (const float*)d_in[12];
    const float* bn1b  = (const float*)d_in[13];
    const float* bn2g  = (const float*)d_in[14];
    const float* bn2b  = (const float*)d_in[15];
    const float* wq    = (const float*)d_in[16];
    const float* bq    = (const float*)d_in[17];
    const float* wk    = (const float*)d_in[18];
    const float* bk    = (const float*)d_in[19];
    const float* wv    = (const float*)d_in[20];
    const float* bv    = (const float*)d_in[21];
    const float* gamma = (const float*)d_in[22];
    float* out = (float*)d_out;

    char* ws = (char*)d_ws;
    float* te    = (float*)(ws + 0);
    float* sums1 = (float*)(ws + 16384);
    float* sums2 = (float*)(ws + 18432);
    char* base = ws + 32768;
    bf16* W3_1 = (bf16*)(base);
    bf16* W3_2 = (bf16*)(base + 1179648);
    bf16* W3_3 = (bf16*)(base + 2359296);
    bf16* Xp0  = (bf16*)(base + 3538944);
    bf16* Xp1  = (bf16*)(base + 13008896);
    bf16* Craw = (bf16*)(base + 22478848);
    bf16* P    = (bf16*)(base);                    // 32 MB alias (dead conv bufs)
    bf16* Yt   = (bf16*)(base + 33554432);
    bf16* QKb  = (bf16*)(base + 41943040);
    bf16* Vb   = (bf16*)(base + 44040192);
    float* invs= (float*)(base + 52428800);
    bf16* WQK  = (bf16*)(base + 52494336);
    bf16* WVb  = (bf16*)(base + 52527104);

    prep_all_k<<<3184, 256, 0, stream>>>(
        x, Xp0, Xp1, sums1,
        t, w_t1, b_t1, w_t2, b_t2, te,
        w_c1, w_c2, w_tr, W3_1, W3_2, W3_3,
        wq, wk, wv, WQK, WVb);

    conv_mfma_k<true, true><<<256, 256, 0, stream>>>(Xp0, W3_1, b_c1, Craw, sums1);
    bn_apply_T_k<true><<<2048, 256, 0, stream>>>(Craw, sums1, bn1g, bn1b, te, Xp1);

    conv_mfma_k<true, true><<<256, 256, 0, stream>>>(Xp1, W3_2, b_c2, Craw, sums2);
    bn_apply_T_k<false><<<2048, 256, 0, stream>>>(Craw, sums2, bn2g, bn2b, nullptr, Xp0);

    conv_mfma_k<false, false><<<256, 256, 0, stream>>>(Xp0, W3_3, b_tr, Yt, nullptr);

    qkv_mfma_k<<<384, 512, 0, stream>>>(WVb, Yt, bv, Vb, WQK, bq, bk, QKb);
    softmax_k<<<512, 256, 0, stream>>>(QKb, P, invs);
    pv_mfma_k<<<256, 256, 0, stream>>>(Vb, P, invs, Yt, gamma, out);
}

// Round 15
// 164.712 us; speedup vs baseline: 1.0075x; 1.0075x over previous
//
#include <hip/hip_runtime.h>
#include <hip/hip_bf16.h>

using bf16 = __hip_bfloat16;

typedef __attribute__((ext_vector_type(8))) short bf16x8_t;
typedef __attribute__((ext_vector_type(4))) float f32x4_t;

__device__ __forceinline__ float b2f(bf16 x){ return __bfloat162float(x); }
__device__ __forceinline__ bf16  f2b(float x){ return __float2bfloat16(x); }
__device__ __forceinline__ unsigned short f2bu(float x){ bf16 h = __float2bfloat16(x); return *(unsigned short*)&h; }
__device__ __forceinline__ float bits2f(unsigned int lo16){ return __uint_as_float(lo16 << 16); }

__device__ __forceinline__ void gload16(const void* g, void* l) {
    __builtin_amdgcn_global_load_lds(
        (const __attribute__((address_space(1))) unsigned int*)g,
        (__attribute__((address_space(3))) unsigned int*)l, 16, 0, 0);
}

// ---------------------------------------------------------------------------
// Dims: B=16, C=256, H=W=32, N=1024, padded P=34x34=1156, Cq=32
// conv/pv: 128x128 tile, 256 thr (4 waves, 2x2), wave tile 64x64 (32.8
// FLOP/LDS-byte vs 21.8 at 64x32 — LDS-read-bound fix), counted vmcnt.
// conv A: halo-slab (staged once per 64-ch chunk). bn_apply separate (r11).
// ---------------------------------------------------------------------------

// ---- mega-prep: [0,1024) prep_x | [1024,1792) conv-w | [1792,2112) qkv-w |
//      [2112,2128) time_mlp | [2128,3184) halo-zero (Xp0+Xp1) ----
__global__ __launch_bounds__(256) void prep_all_k(
    const float* __restrict__ x, bf16* __restrict__ Xp0, bf16* __restrict__ Xp1,
    float* __restrict__ sums,
    const float* __restrict__ t, const float* __restrict__ w_t1, const float* __restrict__ b_t1,
    const float* __restrict__ w_t2, const float* __restrict__ b_t2, float* __restrict__ te,
    const float* __restrict__ w1, const float* __restrict__ w2, const float* __restrict__ w3,
    bf16* __restrict__ W1, bf16* __restrict__ W2, bf16* __restrict__ W3o,
    const float* __restrict__ wq, const float* __restrict__ wk, const float* __restrict__ wv,
    bf16* __restrict__ WQK, bf16* __restrict__ WVb)
{
    __shared__ char smem[64 * 65 * 4];
    const int blk = blockIdx.x;
    const int tid = threadIdx.x;

    if (blk < 1024) {
        float (*xs)[65] = (float(*)[65])smem;
        if (blk == 0) {
            sums[tid] = 0.f; sums[tid + 256] = 0.f; sums[tid + 512] = 0.f; sums[tid + 768] = 0.f;
        }
        const int b = blk >> 6, ct = (blk >> 4) & 3, nt = blk & 15;
        const int c0 = ct << 6, n0 = nt << 6;
        {
            const int cl = tid >> 2, nc = (tid & 3) << 4;
            const float* src = x + (size_t)((b << 8) + c0 + cl) * 1024 + n0 + nc;
            #pragma unroll
            for (int j = 0; j < 16; j += 4) {
                const float4 v = *(const float4*)(src + j);
                xs[cl][nc + j] = v.x; xs[cl][nc + j + 1] = v.y;
                xs[cl][nc + j + 2] = v.z; xs[cl][nc + j + 3] = v.w;
            }
        }
        __syncthreads();
        {
            const int nl = tid >> 2, cc = (tid & 3) << 4;
            const int n = n0 + nl;
            const int p = ((n >> 5) + 1) * 34 + (n & 31) + 1;
            unsigned int u[8];
            #pragma unroll
            for (int k = 0; k < 8; ++k)
                u[k] = (unsigned int)f2bu(xs[cc + 2 * k][nl]) | ((unsigned int)f2bu(xs[cc + 2 * k + 1][nl]) << 16);
            bf16* dst = Xp0 + (size_t)(b * 1156 + p) * 256 + c0 + cc;
            *(uint4*)dst = make_uint4(u[0], u[1], u[2], u[3]);
            *(uint4*)(dst + 8) = make_uint4(u[4], u[5], u[6], u[7]);
        }
    } else if (blk < 1792) {
        float* ls = (float*)smem;
        const int id = blk - 1024;
        const int co = id & 255;
        const int sel = id >> 8;
        const float* w = (sel == 0) ? w1 : (sel == 1) ? w2 : w3;
        bf16* dst = (sel == 0) ? W1 : (sel == 1) ? W2 : W3o;
        const float* src = w + (size_t)co * 2304;
        #pragma unroll
        for (int i = 0; i < 9; ++i) ls[tid + (i << 8)] = src[tid + (i << 8)];
        __syncthreads();
        #pragma unroll
        for (int off = 0; off < 9; ++off)
            dst[(size_t)(co * 9 + off) * 256 + tid] = f2b(ls[tid * 9 + off]);
    } else if (blk < 2112) {
        const int r = blk - 1792;
        if (r < 32)       WQK[r * 256 + tid] = f2b(wq[r * 256 + tid]);
        else if (r < 64)  WQK[r * 256 + tid] = f2b(wk[(r - 32) * 256 + tid]);
        else              WVb[(r - 64) * 256 + tid] = f2b(wv[(r - 64) * 256 + tid]);
    } else if (blk < 2128) {
        float* tr = (float*)smem;
        float* hid = tr + 256;
        const int b = blk - 2112, j = tid;
        tr[j] = t[(b << 8) + j];
        __syncthreads();
        float s = b_t1[j];
        const float* wp = w_t1 + j * 256;
        for (int k = 0; k < 256; ++k) s += tr[k] * wp[k];
        hid[j] = fmaxf(s, 0.f);
        __syncthreads();
        float s2 = b_t2[j];
        const float* wp2 = w_t2 + j * 256;
        for (int k = 0; k < 256; ++k) s2 += hid[k] * wp2[k];
        te[(b << 8) + j] = fmaxf(s2, 0.f);
    } else {
        const int idx = (blk - 2128) * 256 + tid;
        const int v = idx >> 6;
        const int o = (idx & 63) << 1;
        if (v < 4224) {
            const int buf = v / 2112;
            const int rem = v - buf * 2112;
            const int b = rem / 132;
            const int h = rem - b * 132;
            int p;
            if (h < 34)        p = h;
            else if (h < 68)   p = 1122 + (h - 34);
            else if (h < 100)  p = (h - 68 + 1) * 34;
            else               p = (h - 100 + 1) * 34 + 33;
            unsigned int* dst = (unsigned int*)((buf ? Xp1 : Xp0) + (size_t)(b * 1156 + p) * 256);
            dst[o] = 0u; dst[o + 1] = 0u;
        }
    }
}

// ---- conv3x3 halo-slab implicit GEMM: 128x128 tile, 256 thr, 4 waves ----
// Wave tile 64x64 (2x2 wave grid). A slab dbuf (2x32KB), B 3-buf (3x16KB).
// vmcnt ledger: A stage=8 loads, B stage=4. off==8 -> 12, else 4.
template<bool RELU, bool STATS>
__global__ __launch_bounds__(256, 1) void conv_mfma_k(
    const bf16* __restrict__ Xp, const bf16* __restrict__ W3,
    const float* __restrict__ bias, bf16* __restrict__ outp, float* __restrict__ sums)
{
    __shared__ bf16 Als[2][16384];
    __shared__ bf16 Bls[3][8192];
    __shared__ float sstat[256];
    const int tid = threadIdx.x;
    const int wid = tid >> 6, lane = tid & 63;
    const int wm = wid >> 1, wn = wid & 1;
    const int blk = blockIdx.x;
    const int xc = blk & 7, tt = blk >> 3;
    const int b = xc + ((tt >> 4) << 3);
    const int tile = tt & 15, mt = tile >> 1, nt = tile & 1;
    const int m0 = mt << 7, co0 = nt << 7;

    if (STATS) sstat[tid] = 0.f;

    const bf16* xsl = Xp + (size_t)(b * 1156 + mt * 136) * 256;

    // A slab staging: 8 gload16/thread per cic
    const int l8 = lane >> 3;
    const int aj = ((lane & 7) ^ l8) << 3;
    const bf16* agp[8];
    #pragma unroll
    for (int i = 0; i < 8; ++i)
        agp[i] = xsl + (size_t)((i << 5) + (wid << 3) + l8) * 256 + aj;

    // B staging: 4 gload16/thread per step
    const int brr = tid >> 3;                       // 0..31
    const int sL8 = (((tid & 7) ^ (brr & 7)) << 3);
    const bf16* bgp[4];
    #pragma unroll
    for (int i = 0; i < 4; ++i)
        bgp[i] = W3 + (size_t)(co0 + (i << 5) + brr) * 2304 + sL8;

    const int rsel = lane & 15, lg = lane >> 4;
    const int s0 = ((lg ^ (lane & 7)) << 3);
    const int s1 = (((lg + 4) ^ (lane & 7)) << 3);
    const int bbase = ((wn << 6) + rsel) << 6;
    int dbase[4];
    #pragma unroll
    for (int mi = 0; mi < 4; ++mi)
        dbase[mi] = ((wm << 1) + (mi >> 1)) * 34 + ((mi & 1) << 4) + rsel;

    f32x4_t acc[4][4];
    #pragma unroll
    for (int mi = 0; mi < 4; ++mi)
        #pragma unroll
        for (int ni = 0; ni < 4; ++ni)
            acc[mi][ni] = (f32x4_t){0.f, 0.f, 0.f, 0.f};

    auto STAGE_A = [&](int cic, int buf) {
        #pragma unroll
        for (int i = 0; i < 8; ++i)
            gload16(agp[i] + (cic << 6), &Als[buf][(i << 11) + (wid << 9)]);
    };
    auto STAGE_B = [&](int st, int buf) {
        const int koff = ((st % 9) << 8) + ((st / 9) << 6);
        #pragma unroll
        for (int i = 0; i < 4; ++i)
            gload16(bgp[i] + koff, &Bls[buf][(i << 11) + (wid << 9)]);
    };

    STAGE_A(0, 0);
    STAGE_B(0, 0);
    STAGE_B(1, 1);

    #pragma unroll
    for (int st = 0; st < 36; ++st) {
        if (st == 35)           asm volatile("s_waitcnt vmcnt(0)" ::: "memory");
        else if (st % 9 == 8)   asm volatile("s_waitcnt vmcnt(12)" ::: "memory");
        else                    asm volatile("s_waitcnt vmcnt(4)" ::: "memory");
        __builtin_amdgcn_s_barrier();
        asm volatile("" ::: "memory");
        const int cic = st / 9, off = st % 9;
        const int doff = (off / 3) * 34 + (off % 3);
        const bf16* abuf = Als[cic & 1];
        const bf16* bbuf = Bls[st % 3];
        #pragma unroll
        for (int kh = 0; kh < 2; ++kh) {
            const int sk = kh ? s1 : s0;
            bf16x8_t av[4], bv[4];
            #pragma unroll
            for (int mi = 0; mi < 4; ++mi) {
                const int sp = dbase[mi] + doff;
                av[mi] = *(const bf16x8_t*)((const char*)abuf +
                            (sp << 7) + ((((kh << 2) + lg) ^ (sp & 7)) << 4));
            }
            #pragma unroll
            for (int ni = 0; ni < 4; ++ni)
                bv[ni] = *(const bf16x8_t*)(bbuf + bbase + (ni << 10) + sk);
            #pragma unroll
            for (int mi = 0; mi < 4; ++mi)
                #pragma unroll
                for (int ni = 0; ni < 4; ++ni)
                    acc[mi][ni] = __builtin_amdgcn_mfma_f32_16x16x32_bf16(
                        av[mi], bv[ni], acc[mi][ni], 0, 0, 0);
        }
        if (st + 2 < 36) STAGE_B(st + 2, (st + 2) % 3);
        if (off == 7 && st < 27) STAGE_A(cic + 1, (cic + 1) & 1);
    }

    const int cr = lg << 2;
    const int cc = rsel;
    #pragma unroll
    for (int ni = 0; ni < 4; ++ni) {
        const int co = co0 + (wn << 6) + (ni << 4) + cc;
        const float bb = bias[co];
        float ssum = 0.f, ssq = 0.f;
        #pragma unroll
        for (int mi = 0; mi < 4; ++mi) {
            const int nb = m0 + (wm << 6) + (mi << 4) + cr;
            #pragma unroll
            for (int j = 0; j < 4; ++j) {
                float v = acc[mi][ni][j] + bb;
                if (RELU) v = fmaxf(v, 0.f);
                outp[(size_t)((b << 10) + nb + j) * 256 + co] = f2b(v);
                if (STATS) { ssum += v; ssq += v * v; }
            }
        }
        if (STATS) {
            ssum += __shfl_xor(ssum, 16); ssum += __shfl_xor(ssum, 32);
            ssq  += __shfl_xor(ssq, 16);  ssq  += __shfl_xor(ssq, 32);
            if (lane < 16) {
                const int ch = (wn << 6) + (ni << 4) + cc;   // 0..127
                atomicAdd(&sstat[ch * 2], ssum);
                atomicAdd(&sstat[ch * 2 + 1], ssq);
            }
        }
    }
    if (STATS) {
        __syncthreads();
        if (tid < 128) {
            atomicAdd(&sums[co0 + tid], sstat[tid * 2]);
            atomicAdd(&sums[256 + co0 + tid], sstat[tid * 2 + 1]);
        }
    }
}

// bn apply; computes scale/shift from sums locally; writes padded Xp interior
template<bool TE>
__global__ __launch_bounds__(256) void bn_apply_T_k(
    const bf16* __restrict__ a, const float* __restrict__ sums,
    const float* __restrict__ g, const float* __restrict__ bb,
    const float* __restrict__ te, bf16* __restrict__ Xp)
{
    const int t = threadIdx.x;
    const int row = blockIdx.x * 8 + (t >> 5);
    const int c0 = (t & 31) << 3;
    const int b = row >> 10, n = row & 1023;
    const uint4 u = *(const uint4*)(a + (size_t)row * 256 + c0);
    const unsigned int w[4] = {u.x, u.y, u.z, u.w};
    float scv[8], shv[8];
    #pragma unroll
    for (int k = 0; k < 8; ++k) {
        const int c = c0 + k;
        const float m = sums[c] * (1.f / 16384.f);
        const float var = sums[256 + c] * (1.f / 16384.f) - m * m;
        const float sc = g[c] * rsqrtf(var + 1e-5f);
        scv[k] = sc;
        shv[k] = bb[c] - m * sc + (TE ? te[(b << 8) + c] : 0.f);
    }
    unsigned int o[4];
    #pragma unroll
    for (int k = 0; k < 4; ++k) {
        const float v0 = bits2f(w[k] & 0xffffu) * scv[2*k] + shv[2*k];
        const float v1 = __uint_as_float(w[k] & 0xffff0000u) * scv[2*k+1] + shv[2*k+1];
        o[k] = (unsigned int)f2bu(v0) | ((unsigned int)f2bu(v1) << 16);
    }
    const int p = ((n >> 5) + 1) * 34 + (n & 31) + 1;
    *(uint4*)(Xp + (size_t)(b * 1156 + p) * 256 + c0) = make_uint4(o[0], o[1], o[2], o[3]);
}

// ---- merged Q|K + V projections (block-range dispatch, 512 thr) ----
__global__ __launch_bounds__(512, 1) void qkv_mfma_k(
    const bf16* __restrict__ WVb, const bf16* __restrict__ Yt,
    const float* __restrict__ bvp, bf16* __restrict__ Vb,
    const bf16* __restrict__ WQK, const float* __restrict__ bq,
    const float* __restrict__ bk, bf16* __restrict__ QKb)
{
    __shared__ bf16 Als[3][128 * 64];
    __shared__ bf16 Bls[3][128 * 64];
    const int tid = threadIdx.x;
    const int wid = tid >> 6, lane = tid & 63;

    if (blockIdx.x >= 256) {
        const int blk2 = blockIdx.x - 256;
        const int b = blk2 >> 3, m0 = (blk2 & 7) << 7;
        const int n0w = m0 + (wid << 4);
        const bf16* arow = Yt + (size_t)((b << 10) + n0w + (lane & 15)) * 256 + ((lane >> 4) << 3);
        const int boff = ((lane >> 4) << 3);
        f32x4_t acc[4];
        #pragma unroll
        for (int ni = 0; ni < 4; ++ni) acc[ni] = (f32x4_t){0.f,0.f,0.f,0.f};
        for (int k0 = 0; k0 < 256; k0 += 32) {
            const bf16x8_t av = *(const bf16x8_t*)(arow + k0);
            #pragma unroll
            for (int ni = 0; ni < 4; ++ni) {
                const bf16x8_t bv = *(const bf16x8_t*)(WQK + (ni * 16 + (lane & 15)) * 256 + k0 + boff);
                acc[ni] = __builtin_amdgcn_mfma_f32_16x16x32_bf16(av, bv, acc[ni], 0, 0, 0);
            }
        }
        const int cr = (lane >> 4) << 2, cc = lane & 15;
        #pragma unroll
        for (int ni = 0; ni < 4; ++ni) {
            const int q = ni * 16 + cc;
            const float bias = (q < 32) ? bq[q] : bk[q - 32];
            #pragma unroll
            for (int j = 0; j < 4; ++j) {
                const int n = n0w + cr + j;
                QKb[(size_t)((b << 10) + n) * 64 + q] = f2b(acc[ni][j] + bias);
            }
        }
        return;
    }

    const int wm = wid >> 2, wn = wid & 3;
    const int blk = blockIdx.x;
    const int xc = blk & 7, tt = blk >> 3;
    const int b = xc + ((tt >> 4) << 3);
    const int tile = tt & 15, vt = tile >> 3, nt = tile & 7;
    const int v0 = vt << 7, n0 = nt << 7;

    const int lrow = tid >> 3;
    const int sL8 = (((tid & 7) ^ (lrow & 7)) << 3);
    const bf16* agp[2]; const bf16* bgp[2];
    #pragma unroll
    for (int i = 0; i < 2; ++i) {
        const int r = (i << 6) + lrow;
        agp[i] = WVb + (size_t)(v0 + r) * 256 + sL8;
        bgp[i] = Yt + (size_t)((b << 10) + n0 + r) * 256 + sL8;
    }
    const int rsel = lane & 15;
    const int s0 = (((lane >> 4) ^ (lane & 7)) << 3);
    const int s1 = ((((lane >> 4) + 4) ^ (lane & 7)) << 3);
    const int abase = ((wm << 6) + rsel) << 6;
    const int bbase = ((wn << 5) + rsel) << 6;

    f32x4_t acc[4][2];
    #pragma unroll
    for (int mi = 0; mi < 4; ++mi)
        #pragma unroll
        for (int ni = 0; ni < 2; ++ni)
            acc[mi][ni] = (f32x4_t){0.f,0.f,0.f,0.f};

    auto STAGE = [&](int kt2, int buf) {
        const int koff = kt2 << 6;
        #pragma unroll
        for (int i = 0; i < 2; ++i) {
            gload16(agp[i] + koff, &Als[buf][((i << 6) + (wid << 3)) << 6]);
            gload16(bgp[i] + koff, &Bls[buf][((i << 6) + (wid << 3)) << 6]);
        }
    };

    STAGE(0, 0); STAGE(1, 1);
    for (int kt = 0; kt < 4; ++kt) {
        if (kt < 3) asm volatile("s_waitcnt vmcnt(4)" ::: "memory");
        else        asm volatile("s_waitcnt vmcnt(0)" ::: "memory");
        __builtin_amdgcn_s_barrier();
        asm volatile("" ::: "memory");
        const int cur = kt % 3;
        #pragma unroll
        for (int kh = 0; kh < 2; ++kh) {
            const int sk = kh ? s1 : s0;
            bf16x8_t av[4], bv[2];
            #pragma unroll
            for (int mi = 0; mi < 4; ++mi)
                av[mi] = *(const bf16x8_t*)(&Als[cur][abase + (mi << 10) + sk]);
            #pragma unroll
            for (int ni = 0; ni < 2; ++ni)
                bv[ni] = *(const bf16x8_t*)(&Bls[cur][bbase + (ni << 10) + sk]);
            #pragma unroll
            for (int mi = 0; mi < 4; ++mi)
                #pragma unroll
                for (int ni = 0; ni < 2; ++ni)
                    acc[mi][ni] = __builtin_amdgcn_mfma_f32_16x16x32_bf16(
                        av[mi], bv[ni], acc[mi][ni], 0, 0, 0);
        }
        if (kt + 2 < 4) STAGE(kt + 2, (kt + 2) % 3);
    }

    const int cr = (lane >> 4) << 2, cc = lane & 15;
    #pragma unroll
    for (int mi = 0; mi < 4; ++mi) {
        #pragma unroll
        for (int j = 0; j < 4; ++j) {
            const int v = v0 + (wm << 6) + (mi << 4) + cr + j;
            const float bb = bvp[v];
            #pragma unroll
            for (int ni = 0; ni < 2; ++ni) {
                const int n = n0 + (wn << 5) + (ni << 4) + cc;
                Vb[(size_t)((b << 8) + v) * 1024 + n] = f2b(acc[mi][ni][j] + bb);
            }
        }
    }
}

// scores + softmax (unnormalized P, deferred 1/sum)
__global__ __launch_bounds__(256) void softmax_k(
    const bf16* __restrict__ QKb, bf16* __restrict__ P, float* __restrict__ invs)
{
    const int b = blockIdx.x >> 5, n0 = (blockIdx.x & 31) << 5;
    const int tid = threadIdx.x, wid = tid >> 6, lane = tid & 63;
    const int m0w = wid << 8;
    __shared__ float wred[4][32];

    const bf16* qbase = QKb + (size_t)((b << 10) + n0) * 64;
    const int koff = (lane >> 4) << 3;
    bf16x8_t qf[2];
    #pragma unroll
    for (int nt = 0; nt < 2; ++nt)
        qf[nt] = *(const bf16x8_t*)(qbase + (nt * 16 + (lane & 15)) * 64 + koff);
    const bf16* kbase = QKb + (size_t)(b << 10) * 64 + 32;

    float mx[2] = {-3.0e38f, -3.0e38f};
    for (int mi = 0; mi < 16; ++mi) {
        const bf16x8_t kf = *(const bf16x8_t*)(kbase + (m0w + mi * 16 + (lane & 15)) * 64 + koff);
        #pragma unroll
        for (int nt = 0; nt < 2; ++nt) {
            f32x4_t s = (f32x4_t){0.f,0.f,0.f,0.f};
            s = __builtin_amdgcn_mfma_f32_16x16x32_bf16(kf, qf[nt], s, 0, 0, 0);
            mx[nt] = fmaxf(mx[nt], fmaxf(fmaxf(s[0], s[1]), fmaxf(s[2], s[3])));
        }
    }
    #pragma unroll
    for (int nt = 0; nt < 2; ++nt) {
        mx[nt] = fmaxf(mx[nt], __shfl_xor(mx[nt], 16));
        mx[nt] = fmaxf(mx[nt], __shfl_xor(mx[nt], 32));
        if (lane < 16) wred[wid][nt * 16 + lane] = mx[nt];
    }
    __syncthreads();
    float rm[2];
    #pragma unroll
    for (int nt = 0; nt < 2; ++nt) {
        const int c = nt * 16 + (lane & 15);
        rm[nt] = fmaxf(fmaxf(wred[0][c], wred[1][c]), fmaxf(wred[2][c], wred[3][c]));
    }
    __syncthreads();

    float sm[2] = {0.f, 0.f};
    for (int mi = 0; mi < 16; ++mi) {
        const bf16x8_t kf = *(const bf16x8_t*)(kbase + (m0w + mi * 16 + (lane & 15)) * 64 + koff);
        #pragma unroll
        for (int nt = 0; nt < 2; ++nt) {
            f32x4_t s = (f32x4_t){0.f,0.f,0.f,0.f};
            s = __builtin_amdgcn_mfma_f32_16x16x32_bf16(kf, qf[nt], s, 0, 0, 0);
            const float p0 = __expf(s[0] - rm[nt]);
            const float p1 = __expf(s[1] - rm[nt]);
            const float p2 = __expf(s[2] - rm[nt]);
            const float p3 = __expf(s[3] - rm[nt]);
            sm[nt] += (p0 + p1) + (p2 + p3);
            uint2 u;
            u.x = (unsigned int)f2bu(p0) | ((unsigned int)f2bu(p1) << 16);
            u.y = (unsigned int)f2bu(p2) | ((unsigned int)f2bu(p3) << 16);
            const int n = n0 + nt * 16 + (lane & 15);
            const int m = m0w + mi * 16 + ((lane >> 4) << 2);
            *(uint2*)(P + (size_t)((b << 10) + n) * 1024 + m) = u;
        }
    }
    #pragma unroll
    for (int nt = 0; nt < 2; ++nt) {
        sm[nt] += __shfl_xor(sm[nt], 16);
        sm[nt] += __shfl_xor(sm[nt], 32);
        if (lane < 16) wred[wid][nt * 16 + lane] = sm[nt];
    }
    __syncthreads();
    if (tid < 32) {
        const float total = wred[0][tid] + wred[1][tid] + wred[2][tid] + wred[3][tid];
        invs[(b << 10) + n0 + tid] = 1.f / total;
    }
}

// PV + residual: 128x128 tile, 256 thr, 4 waves (64x64 wave tile), K=1024.
__global__ __launch_bounds__(256, 1) void pv_mfma_k(
    const bf16* __restrict__ Vb, const bf16* __restrict__ P,
    const float* __restrict__ invs, const bf16* __restrict__ Yt,
    const float* __restrict__ gamma, float* __restrict__ out)
{
    __shared__ bf16 Als[3][8192];
    __shared__ bf16 Bls[3][8192];
    const int tid = threadIdx.x;
    const int wid = tid >> 6, lane = tid & 63;
    const int wm = wid >> 1, wn = wid & 1;
    const int blk = blockIdx.x;
    const int xc = blk & 7, tt = blk >> 3;
    const int b = xc + ((tt >> 4) << 3);
    const int tile = tt & 15, ct = tile >> 3, nt = tile & 7;
    const int c0 = ct << 7, n0 = nt << 7;

    const int brr = tid >> 3;
    const int sL8 = (((tid & 7) ^ (brr & 7)) << 3);
    const bf16* agp[4]; const bf16* bgp[4];
    #pragma unroll
    for (int i = 0; i < 4; ++i) {
        const int r = (i << 5) + brr;
        agp[i] = Vb + (size_t)((b << 8) + c0 + r) * 1024 + sL8;
        bgp[i] = P + (size_t)((b << 10) + n0 + r) * 1024 + sL8;
    }
    const int rsel = lane & 15, lg = lane >> 4;
    const int s0 = ((lg ^ (lane & 7)) << 3);
    const int s1 = (((lg + 4) ^ (lane & 7)) << 3);
    const int abase = ((wm << 6) + rsel) << 6;
    const int bbase = ((wn << 6) + rsel) << 6;

    f32x4_t acc[4][4];
    #pragma unroll
    for (int mi = 0; mi < 4; ++mi)
        #pragma unroll
        for (int ni = 0; ni < 4; ++ni)
            acc[mi][ni] = (f32x4_t){0.f,0.f,0.f,0.f};

    auto STAGE = [&](int kt2, int buf) {
        const int koff = kt2 << 6;
        #pragma unroll
        for (int i = 0; i < 4; ++i) {
            gload16(agp[i] + koff, &Als[buf][(i << 11) + (wid << 9)]);
            gload16(bgp[i] + koff, &Bls[buf][(i << 11) + (wid << 9)]);
        }
    };

    STAGE(0, 0); STAGE(1, 1);
    #pragma unroll
    for (int kt = 0; kt < 16; ++kt) {
        if (kt < 15) asm volatile("s_waitcnt vmcnt(8)" ::: "memory");
        else         asm volatile("s_waitcnt vmcnt(0)" ::: "memory");
        __builtin_amdgcn_s_barrier();
        asm volatile("" ::: "memory");
        const int cur = kt % 3;
        #pragma unroll
        for (int kh = 0; kh < 2; ++kh) {
            const int sk = kh ? s1 : s0;
            bf16x8_t av[4], bv[4];
            #pragma unroll
            for (int mi = 0; mi < 4; ++mi)
                av[mi] = *(const bf16x8_t*)(&Als[cur][abase + (mi << 10) + sk]);
            #pragma unroll
            for (int ni = 0; ni < 4; ++ni)
                bv[ni] = *(const bf16x8_t*)(&Bls[cur][bbase + (ni << 10) + sk]);
            #pragma unroll
            for (int mi = 0; mi < 4; ++mi)
                #pragma unroll
                for (int ni = 0; ni < 4; ++ni)
                    acc[mi][ni] = __builtin_amdgcn_mfma_f32_16x16x32_bf16(
                        av[mi], bv[ni], acc[mi][ni], 0, 0, 0);
        }
        if (kt + 2 < 16) STAGE(kt + 2, (kt + 2) % 3);
    }

    const float g = gamma[0];
    const int cr = lg << 2, cc = rsel;
    #pragma unroll
    for (int ni = 0; ni < 4; ++ni) {
        const int n = n0 + (wn << 6) + (ni << 4) + cc;
        const float gi = g * invs[(b << 10) + n];
        #pragma unroll
        for (int mi = 0; mi < 4; ++mi) {
            const int c = c0 + (wm << 6) + (mi << 4) + cr;
            const bf16* yp = Yt + (size_t)((b << 10) + n) * 256 + c;
            #pragma unroll
            for (int j = 0; j < 4; ++j)
                out[(size_t)((b << 8) + c + j) * 1024 + n] = gi * acc[mi][ni][j] + b2f(yp[j]);
        }
    }
}

// ---------------------------------------------------------------------------
// Workspace (base = ws+32K; round-11 layout):
//  te ws+0 | sums1 ws+16384 | sums2 ws+18432
//  W3_1 [0) W3_2 [1179648) W3_3 [2359296) Xp0 [3538944) Xp1 [13008896)
//  Craw [22478848)  P [0,32M) alias  Yt [33554432) QKb [41943040)
//  Vb [44040192) invs [52428800) WQK [52494336) WVb [52527104)
// ---------------------------------------------------------------------------
extern "C" void kernel_launch(void* const* d_in, const int* in_sizes, int n_in,
                              void* d_out, int out_size, void* d_ws, size_t ws_size,
                              hipStream_t stream)
{
    const float* x     = (const float*)d_in[0];
    const float* t     = (const float*)d_in[1];
    const float* w_t1  = (const float*)d_in[2];
    const float* b_t1  = (const float*)d_in[3];
    const float* w_t2  = (const float*)d_in[4];
    const float* b_t2  = (const float*)d_in[5];
    const float* w_c1  = (const float*)d_in[6];
    const float* b_c1  = (const float*)d_in[7];
    const float* w_c2  = (const float*)d_in[8];
    const float* b_c2  = (const float*)d_in[9];
    const float* w_tr  = (const float*)d_in[10];
    const float* b_tr  = (const float*)d_in[11];
    const float* bn1g  = (const float*)d_in[12];
    const float* bn1b  = (const float*)d_in[13];
    const float* bn2g  = (const float*)d_in[14];
    const float* bn2b  = (const float*)d_in[15];
    const float* wq    = (const float*)d_in[16];
    const float* bq    = (const float*)d_in[17];
    const float* wk    = (const float*)d_in[18];
    const float* bk    = (const float*)d_in[19];
    const float* wv    = (const float*)d_in[20];
    const float* bv    = (const float*)d_in[21];
    const float* gamma = (const float*)d_in[22];
    float* out = (float*)d_out;

    char* ws = (char*)d_ws;
    float* te    = (float*)(ws + 0);
    float* sums1 = (float*)(ws + 16384);
    float* sums2 = (float*)(ws + 18432);
    char* base = ws + 32768;
    bf16* W3_1 = (bf16*)(base);
    bf16* W3_2 = (bf16*)(base + 1179648);
    bf16* W3_3 = (bf16*)(base + 2359296);
    bf16* Xp0  = (bf16*)(base + 3538944);
    bf16* Xp1  = (bf16*)(base + 13008896);
    bf16* Craw = (bf16*)(base + 22478848);
    bf16* P    = (bf16*)(base);                    // 32 MB alias (dead conv bufs)
    bf16* Yt   = (bf16*)(base + 33554432);
    bf16* QKb  = (bf16*)(base + 41943040);
    bf16* Vb   = (bf16*)(base + 44040192);
    float* invs= (float*)(base + 52428800);
    bf16* WQK  = (bf16*)(base + 52494336);
    bf16* WVb  = (bf16*)(base + 52527104);

    prep_all_k<<<3184, 256, 0, stream>>>(
        x, Xp0, Xp1, sums1,
        t, w_t1, b_t1, w_t2, b_t2, te,
        w_c1, w_c2, w_tr, W3_1, W3_2, W3_3,
        wq, wk, wv, WQK, WVb);

    conv_mfma_k<true, true><<<256, 256, 0, stream>>>(Xp0, W3_1, b_c1, Craw, sums1);
    bn_apply_T_k<true><<<2048, 256, 0, stream>>>(Craw, sums1, bn1g, bn1b, te, Xp1);

    conv_mfma_k<true, true><<<256, 256, 0, stream>>>(Xp1, W3_2, b_c2, Craw, sums2);
    bn_apply_T_k<false><<<2048, 256, 0, stream>>>(Craw, sums2, bn2g, bn2b, nullptr, Xp0);

    conv_mfma_k<false, false><<<256, 256, 0, stream>>>(Xp0, W3_3, b_tr, Yt, nullptr);

    qkv_mfma_k<<<384, 512, 0, stream>>>(WVb, Yt, bv, Vb, WQK, bq, bk, QKb);
    softmax_k<<<512, 256, 0, stream>>>(QKb, P, invs);
    pv_mfma_k<<<256, 256, 0, stream>>>(Vb, P, invs, Yt, gamma, out);
}

// Round 16
// 149.428 us; speedup vs baseline: 1.1106x; 1.1023x over previous
//
#include <hip/hip_runtime.h>
#include <hip/hip_bf16.h>

using bf16 = __hip_bfloat16;

typedef __attribute__((ext_vector_type(8))) short bf16x8_t;
typedef __attribute__((ext_vector_type(4))) float f32x4_t;

__device__ __forceinline__ float b2f(bf16 x){ return __bfloat162float(x); }
__device__ __forceinline__ bf16  f2b(float x){ return __float2bfloat16(x); }
__device__ __forceinline__ unsigned short f2bu(float x){ bf16 h = __float2bfloat16(x); return *(unsigned short*)&h; }
__device__ __forceinline__ float bits2f(unsigned int lo16){ return __uint_as_float(lo16 << 16); }

__device__ __forceinline__ void gload16(const void* g, void* l) {
    __builtin_amdgcn_global_load_lds(
        (const __attribute__((address_space(1))) unsigned int*)g,
        (__attribute__((address_space(3))) unsigned int*)l, 16, 0, 0);
}

// ---------------------------------------------------------------------------
// Dims: B=16, C=256, H=W=32, N=1024, padded P=34x34=1156, Cq=32
// ROUND-11 STRUCTURE (best: 150.7us) + conv vmcnt ledger fix at off==8.
// conv: halo-slab implicit GEMM, 512 thr / 8 waves (64x32 wave tiles).
// pv: 128x128 3-buf depth-2 at 512 thr. qkv merged. bn_apply separate.
// ---------------------------------------------------------------------------

// ---- mega-prep: [0,1024) prep_x | [1024,1792) conv-w | [1792,2112) qkv-w |
//      [2112,2128) time_mlp | [2128,3184) halo-zero (Xp0+Xp1) ----
__global__ __launch_bounds__(256) void prep_all_k(
    const float* __restrict__ x, bf16* __restrict__ Xp0, bf16* __restrict__ Xp1,
    float* __restrict__ sums,
    const float* __restrict__ t, const float* __restrict__ w_t1, const float* __restrict__ b_t1,
    const float* __restrict__ w_t2, const float* __restrict__ b_t2, float* __restrict__ te,
    const float* __restrict__ w1, const float* __restrict__ w2, const float* __restrict__ w3,
    bf16* __restrict__ W1, bf16* __restrict__ W2, bf16* __restrict__ W3o,
    const float* __restrict__ wq, const float* __restrict__ wk, const float* __restrict__ wv,
    bf16* __restrict__ WQK, bf16* __restrict__ WVb)
{
    __shared__ char smem[64 * 65 * 4];
    const int blk = blockIdx.x;
    const int tid = threadIdx.x;

    if (blk < 1024) {
        float (*xs)[65] = (float(*)[65])smem;
        if (blk == 0) {
            sums[tid] = 0.f; sums[tid + 256] = 0.f; sums[tid + 512] = 0.f; sums[tid + 768] = 0.f;
        }
        const int b = blk >> 6, ct = (blk >> 4) & 3, nt = blk & 15;
        const int c0 = ct << 6, n0 = nt << 6;
        {
            const int cl = tid >> 2, nc = (tid & 3) << 4;
            const float* src = x + (size_t)((b << 8) + c0 + cl) * 1024 + n0 + nc;
            #pragma unroll
            for (int j = 0; j < 16; j += 4) {
                const float4 v = *(const float4*)(src + j);
                xs[cl][nc + j] = v.x; xs[cl][nc + j + 1] = v.y;
                xs[cl][nc + j + 2] = v.z; xs[cl][nc + j + 3] = v.w;
            }
        }
        __syncthreads();
        {
            const int nl = tid >> 2, cc = (tid & 3) << 4;
            const int n = n0 + nl;
            const int p = ((n >> 5) + 1) * 34 + (n & 31) + 1;
            unsigned int u[8];
            #pragma unroll
            for (int k = 0; k < 8; ++k)
                u[k] = (unsigned int)f2bu(xs[cc + 2 * k][nl]) | ((unsigned int)f2bu(xs[cc + 2 * k + 1][nl]) << 16);
            bf16* dst = Xp0 + (size_t)(b * 1156 + p) * 256 + c0 + cc;
            *(uint4*)dst = make_uint4(u[0], u[1], u[2], u[3]);
            *(uint4*)(dst + 8) = make_uint4(u[4], u[5], u[6], u[7]);
        }
    } else if (blk < 1792) {
        float* ls = (float*)smem;
        const int id = blk - 1024;
        const int co = id & 255;
        const int sel = id >> 8;
        const float* w = (sel == 0) ? w1 : (sel == 1) ? w2 : w3;
        bf16* dst = (sel == 0) ? W1 : (sel == 1) ? W2 : W3o;
        const float* src = w + (size_t)co * 2304;
        #pragma unroll
        for (int i = 0; i < 9; ++i) ls[tid + (i << 8)] = src[tid + (i << 8)];
        __syncthreads();
        #pragma unroll
        for (int off = 0; off < 9; ++off)
            dst[(size_t)(co * 9 + off) * 256 + tid] = f2b(ls[tid * 9 + off]);
    } else if (blk < 2112) {
        const int r = blk - 1792;
        if (r < 32)       WQK[r * 256 + tid] = f2b(wq[r * 256 + tid]);
        else if (r < 64)  WQK[r * 256 + tid] = f2b(wk[(r - 32) * 256 + tid]);
        else              WVb[(r - 64) * 256 + tid] = f2b(wv[(r - 64) * 256 + tid]);
    } else if (blk < 2128) {
        float* tr = (float*)smem;
        float* hid = tr + 256;
        const int b = blk - 2112, j = tid;
        tr[j] = t[(b << 8) + j];
        __syncthreads();
        float s = b_t1[j];
        const float* wp = w_t1 + j * 256;
        for (int k = 0; k < 256; ++k) s += tr[k] * wp[k];
        hid[j] = fmaxf(s, 0.f);
        __syncthreads();
        float s2 = b_t2[j];
        const float* wp2 = w_t2 + j * 256;
        for (int k = 0; k < 256; ++k) s2 += hid[k] * wp2[k];
        te[(b << 8) + j] = fmaxf(s2, 0.f);
    } else {
        const int idx = (blk - 2128) * 256 + tid;
        const int v = idx >> 6;
        const int o = (idx & 63) << 1;
        if (v < 4224) {
            const int buf = v / 2112;
            const int rem = v - buf * 2112;
            const int b = rem / 132;
            const int h = rem - b * 132;
            int p;
            if (h < 34)        p = h;
            else if (h < 68)   p = 1122 + (h - 34);
            else if (h < 100)  p = (h - 68 + 1) * 34;
            else               p = (h - 100 + 1) * 34 + 33;
            unsigned int* dst = (unsigned int*)((buf ? Xp1 : Xp0) + (size_t)(b * 1156 + p) * 256);
            dst[o] = 0u; dst[o + 1] = 0u;
        }
    }
}

// ---- conv3x3 halo-slab implicit GEMM: 128x128 tile, 512 thr ----
// A: 256-pixel x 64-ch slab staged once per cic (dbuf, 2x32KB); the 9 filter
// offsets are LDS offset re-reads. B: streamed 16KB/step (3-buf, depth-2).
// vmcnt ledger (A=4 loads, B=2): off==8 -> 6 (don't force-drain A prefetch),
// else 2; last step 0.
template<bool RELU, bool STATS>
__global__ __launch_bounds__(512, 1) void conv_mfma_k(
    const bf16* __restrict__ Xp, const bf16* __restrict__ W3,
    const float* __restrict__ bias, bf16* __restrict__ outp, float* __restrict__ sums)
{
    __shared__ bf16 Als[2][16384];
    __shared__ bf16 Bls[3][8192];
    __shared__ float sstat[256];
    const int tid = threadIdx.x;
    const int wid = tid >> 6, lane = tid & 63;
    const int wm = wid >> 2, wn = wid & 3;
    const int blk = blockIdx.x;
    const int xc = blk & 7, tt = blk >> 3;
    const int b = xc + ((tt >> 4) << 3);
    const int tile = tt & 15, mt = tile >> 1, nt = tile & 1;
    const int m0 = mt << 7, co0 = nt << 7;

    if (STATS && tid < 256) sstat[tid] = 0.f;

    const bf16* xsl = Xp + (size_t)(b * 1156 + mt * 136) * 256;

    const int lrow = tid >> 3;
    const int sL8 = (((tid & 7) ^ (lrow & 7)) << 3);
    const bf16* bgp[2];
    #pragma unroll
    for (int i = 0; i < 2; ++i)
        bgp[i] = W3 + (size_t)(co0 + (i << 6) + lrow) * 2304 + sL8;

    const int apix = (wid << 3) + (lane >> 3);
    const int aj0 = lane & 7;

    const int rsel = lane & 15, lg = lane >> 4;
    const int s0 = ((lg ^ (lane & 7)) << 3);
    const int s1 = (((lg + 4) ^ (lane & 7)) << 3);
    const int bbase = ((wn << 5) + rsel) << 6;
    int dbase[4];
    #pragma unroll
    for (int mi = 0; mi < 4; ++mi)
        dbase[mi] = ((wm << 1) + (mi >> 1)) * 34 + ((mi & 1) << 4) + rsel;

    f32x4_t acc[4][2];
    #pragma unroll
    for (int mi = 0; mi < 4; ++mi)
        #pragma unroll
        for (int ni = 0; ni < 2; ++ni)
            acc[mi][ni] = (f32x4_t){0.f, 0.f, 0.f, 0.f};

    auto STAGE_A = [&](int cic, int buf) {
        #pragma unroll
        for (int i = 0; i < 4; ++i) {
            const int pix = (i << 6) + apix;
            const int j = aj0 ^ (pix & 7);
            gload16(xsl + (size_t)pix * 256 + (cic << 6) + (j << 3),
                    &Als[buf][((i << 9) + (wid << 6)) << 3]);
        }
    };
    auto STAGE_B = [&](int st, int buf) {
        const int koff = ((st % 9) << 8) + ((st / 9) << 6);
        #pragma unroll
        for (int i = 0; i < 2; ++i)
            gload16(bgp[i] + koff, &Bls[buf][((i << 6) + (wid << 3)) << 6]);
    };

    STAGE_A(0, 0);
    STAGE_B(0, 0);
    STAGE_B(1, 1);

    #pragma unroll
    for (int st = 0; st < 36; ++st) {
        if (st == 35)         asm volatile("s_waitcnt vmcnt(0)" ::: "memory");
        else if (st % 9 == 8) asm volatile("s_waitcnt vmcnt(6)" ::: "memory");
        else                  asm volatile("s_waitcnt vmcnt(2)" ::: "memory");
        __builtin_amdgcn_s_barrier();
        asm volatile("" ::: "memory");
        const int cic = st / 9, off = st % 9;
        const int doff = (off / 3) * 34 + (off % 3);
        const bf16* abuf = Als[cic & 1];
        const bf16* bbuf = Bls[st % 3];
        #pragma unroll
        for (int kh = 0; kh < 2; ++kh) {
            const int sk = kh ? s1 : s0;
            bf16x8_t av[4], bv[2];
            #pragma unroll
            for (int mi = 0; mi < 4; ++mi) {
                const int sp = dbase[mi] + doff;
                av[mi] = *(const bf16x8_t*)((const char*)abuf +
                            (sp << 7) + ((((kh << 2) + lg) ^ (sp & 7)) << 4));
            }
            #pragma unroll
            for (int ni = 0; ni < 2; ++ni)
                bv[ni] = *(const bf16x8_t*)(bbuf + bbase + (ni << 10) + sk);
            #pragma unroll
            for (int mi = 0; mi < 4; ++mi)
                #pragma unroll
                for (int ni = 0; ni < 2; ++ni)
                    acc[mi][ni] = __builtin_amdgcn_mfma_f32_16x16x32_bf16(
                        av[mi], bv[ni], acc[mi][ni], 0, 0, 0);
        }
        if (st + 2 < 36) STAGE_B(st + 2, (st + 2) % 3);
        if (off == 7 && st < 27) STAGE_A(cic + 1, (cic + 1) & 1);
    }

    const int cr = lg << 2;
    const int cc = rsel;
    #pragma unroll
    for (int ni = 0; ni < 2; ++ni) {
        const int co = co0 + (wn << 5) + (ni << 4) + cc;
        const float bb = bias[co];
        float ssum = 0.f, ssq = 0.f;
        #pragma unroll
        for (int mi = 0; mi < 4; ++mi) {
            const int n = m0 + (wm << 6) + (mi << 4) + cr;
            #pragma unroll
            for (int j = 0; j < 4; ++j) {
                float v = acc[mi][ni][j] + bb;
                if (RELU) v = fmaxf(v, 0.f);
                outp[(size_t)((b << 10) + n + j) * 256 + co] = f2b(v);
                if (STATS) { ssum += v; ssq += v * v; }
            }
        }
        if (STATS) {
            ssum += __shfl_xor(ssum, 16); ssum += __shfl_xor(ssum, 32);
            ssq  += __shfl_xor(ssq, 16);  ssq  += __shfl_xor(ssq, 32);
            if (lane < 16) {
                const int ch = (wn << 5) + (ni << 4) + cc;
                atomicAdd(&sstat[ch * 2], ssum);
                atomicAdd(&sstat[ch * 2 + 1], ssq);
            }
        }
    }
    if (STATS) {
        __syncthreads();
        if (tid < 128) {
            atomicAdd(&sums[co0 + tid], sstat[tid * 2]);
            atomicAdd(&sums[256 + co0 + tid], sstat[tid * 2 + 1]);
        }
    }
}

// bn apply; computes scale/shift from sums locally; writes padded Xp interior
template<bool TE>
__global__ __launch_bounds__(256) void bn_apply_T_k(
    const bf16* __restrict__ a, const float* __restrict__ sums,
    const float* __restrict__ g, const float* __restrict__ bb,
    const float* __restrict__ te, bf16* __restrict__ Xp)
{
    const int t = threadIdx.x;
    const int row = blockIdx.x * 8 + (t >> 5);
    const int c0 = (t & 31) << 3;
    const int b = row >> 10, n = row & 1023;
    const uint4 u = *(const uint4*)(a + (size_t)row * 256 + c0);
    const unsigned int w[4] = {u.x, u.y, u.z, u.w};
    float scv[8], shv[8];
    #pragma unroll
    for (int k = 0; k < 8; ++k) {
        const int c = c0 + k;
        const float m = sums[c] * (1.f / 16384.f);
        const float var = sums[256 + c] * (1.f / 16384.f) - m * m;
        const float sc = g[c] * rsqrtf(var + 1e-5f);
        scv[k] = sc;
        shv[k] = bb[c] - m * sc + (TE ? te[(b << 8) + c] : 0.f);
    }
    unsigned int o[4];
    #pragma unroll
    for (int k = 0; k < 4; ++k) {
        const float v0 = bits2f(w[k] & 0xffffu) * scv[2*k] + shv[2*k];
        const float v1 = __uint_as_float(w[k] & 0xffff0000u) * scv[2*k+1] + shv[2*k+1];
        o[k] = (unsigned int)f2bu(v0) | ((unsigned int)f2bu(v1) << 16);
    }
    const int p = ((n >> 5) + 1) * 34 + (n & 31) + 1;
    *(uint4*)(Xp + (size_t)(b * 1156 + p) * 256 + c0) = make_uint4(o[0], o[1], o[2], o[3]);
}

// ---- merged Q|K + V projections (block-range dispatch, 512 thr) ----
__global__ __launch_bounds__(512, 1) void qkv_mfma_k(
    const bf16* __restrict__ WVb, const bf16* __restrict__ Yt,
    const float* __restrict__ bvp, bf16* __restrict__ Vb,
    const bf16* __restrict__ WQK, const float* __restrict__ bq,
    const float* __restrict__ bk, bf16* __restrict__ QKb)
{
    __shared__ bf16 Als[3][128 * 64];
    __shared__ bf16 Bls[3][128 * 64];
    const int tid = threadIdx.x;
    const int wid = tid >> 6, lane = tid & 63;

    if (blockIdx.x >= 256) {
        const int blk2 = blockIdx.x - 256;
        const int b = blk2 >> 3, m0 = (blk2 & 7) << 7;
        const int n0w = m0 + (wid << 4);
        const bf16* arow = Yt + (size_t)((b << 10) + n0w + (lane & 15)) * 256 + ((lane >> 4) << 3);
        const int boff = ((lane >> 4) << 3);
        f32x4_t acc[4];
        #pragma unroll
        for (int ni = 0; ni < 4; ++ni) acc[ni] = (f32x4_t){0.f,0.f,0.f,0.f};
        for (int k0 = 0; k0 < 256; k0 += 32) {
            const bf16x8_t av = *(const bf16x8_t*)(arow + k0);
            #pragma unroll
            for (int ni = 0; ni < 4; ++ni) {
                const bf16x8_t bv = *(const bf16x8_t*)(WQK + (ni * 16 + (lane & 15)) * 256 + k0 + boff);
                acc[ni] = __builtin_amdgcn_mfma_f32_16x16x32_bf16(av, bv, acc[ni], 0, 0, 0);
            }
        }
        const int cr = (lane >> 4) << 2, cc = lane & 15;
        #pragma unroll
        for (int ni = 0; ni < 4; ++ni) {
            const int q = ni * 16 + cc;
            const float bias = (q < 32) ? bq[q] : bk[q - 32];
            #pragma unroll
            for (int j = 0; j < 4; ++j) {
                const int n = n0w + cr + j;
                QKb[(size_t)((b << 10) + n) * 64 + q] = f2b(acc[ni][j] + bias);
            }
        }
        return;
    }

    const int wm = wid >> 2, wn = wid & 3;
    const int blk = blockIdx.x;
    const int xc = blk & 7, tt = blk >> 3;
    const int b = xc + ((tt >> 4) << 3);
    const int tile = tt & 15, vt = tile >> 3, nt = tile & 7;
    const int v0 = vt << 7, n0 = nt << 7;

    const int lrow = tid >> 3;
    const int sL8 = (((tid & 7) ^ (lrow & 7)) << 3);
    const bf16* agp[2]; const bf16* bgp[2];
    #pragma unroll
    for (int i = 0; i < 2; ++i) {
        const int r = (i << 6) + lrow;
        agp[i] = WVb + (size_t)(v0 + r) * 256 + sL8;
        bgp[i] = Yt + (size_t)((b << 10) + n0 + r) * 256 + sL8;
    }
    const int rsel = lane & 15;
    const int s0 = (((lane >> 4) ^ (lane & 7)) << 3);
    const int s1 = ((((lane >> 4) + 4) ^ (lane & 7)) << 3);
    const int abase = ((wm << 6) + rsel) << 6;
    const int bbase = ((wn << 5) + rsel) << 6;

    f32x4_t acc[4][2];
    #pragma unroll
    for (int mi = 0; mi < 4; ++mi)
        #pragma unroll
        for (int ni = 0; ni < 2; ++ni)
            acc[mi][ni] = (f32x4_t){0.f,0.f,0.f,0.f};

    auto STAGE = [&](int kt2, int buf) {
        const int koff = kt2 << 6;
        #pragma unroll
        for (int i = 0; i < 2; ++i) {
            gload16(agp[i] + koff, &Als[buf][((i << 6) + (wid << 3)) << 6]);
            gload16(bgp[i] + koff, &Bls[buf][((i << 6) + (wid << 3)) << 6]);
        }
    };

    STAGE(0, 0); STAGE(1, 1);
    for (int kt = 0; kt < 4; ++kt) {
        if (kt < 3) asm volatile("s_waitcnt vmcnt(4)" ::: "memory");
        else        asm volatile("s_waitcnt vmcnt(0)" ::: "memory");
        __builtin_amdgcn_s_barrier();
        asm volatile("" ::: "memory");
        const int cur = kt % 3;
        #pragma unroll
        for (int kh = 0; kh < 2; ++kh) {
            const int sk = kh ? s1 : s0;
            bf16x8_t av[4], bv[2];
            #pragma unroll
            for (int mi = 0; mi < 4; ++mi)
                av[mi] = *(const bf16x8_t*)(&Als[cur][abase + (mi << 10) + sk]);
            #pragma unroll
            for (int ni = 0; ni < 2; ++ni)
                bv[ni] = *(const bf16x8_t*)(&Bls[cur][bbase + (ni << 10) + sk]);
            #pragma unroll
            for (int mi = 0; mi < 4; ++mi)
                #pragma unroll
                for (int ni = 0; ni < 2; ++ni)
                    acc[mi][ni] = __builtin_amdgcn_mfma_f32_16x16x32_bf16(
                        av[mi], bv[ni], acc[mi][ni], 0, 0, 0);
        }
        if (kt + 2 < 4) STAGE(kt + 2, (kt + 2) % 3);
    }

    const int cr = (lane >> 4) << 2, cc = lane & 15;
    #pragma unroll
    for (int mi = 0; mi < 4; ++mi) {
        #pragma unroll
        for (int j = 0; j < 4; ++j) {
            const int v = v0 + (wm << 6) + (mi << 4) + cr + j;
            const float bb = bvp[v];
            #pragma unroll
            for (int ni = 0; ni < 2; ++ni) {
                const int n = n0 + (wn << 5) + (ni << 4) + cc;
                Vb[(size_t)((b << 8) + v) * 1024 + n] = f2b(acc[mi][ni][j] + bb);
            }
        }
    }
}

// scores + softmax (unnormalized P, deferred 1/sum)
__global__ __launch_bounds__(256) void softmax_k(
    const bf16* __restrict__ QKb, bf16* __restrict__ P, float* __restrict__ invs)
{
    const int b = blockIdx.x >> 5, n0 = (blockIdx.x & 31) << 5;
    const int tid = threadIdx.x, wid = tid >> 6, lane = tid & 63;
    const int m0w = wid << 8;
    __shared__ float wred[4][32];

    const bf16* qbase = QKb + (size_t)((b << 10) + n0) * 64;
    const int koff = (lane >> 4) << 3;
    bf16x8_t qf[2];
    #pragma unroll
    for (int nt = 0; nt < 2; ++nt)
        qf[nt] = *(const bf16x8_t*)(qbase + (nt * 16 + (lane & 15)) * 64 + koff);
    const bf16* kbase = QKb + (size_t)(b << 10) * 64 + 32;

    float mx[2] = {-3.0e38f, -3.0e38f};
    for (int mi = 0; mi < 16; ++mi) {
        const bf16x8_t kf = *(const bf16x8_t*)(kbase + (m0w + mi * 16 + (lane & 15)) * 64 + koff);
        #pragma unroll
        for (int nt = 0; nt < 2; ++nt) {
            f32x4_t s = (f32x4_t){0.f,0.f,0.f,0.f};
            s = __builtin_amdgcn_mfma_f32_16x16x32_bf16(kf, qf[nt], s, 0, 0, 0);
            mx[nt] = fmaxf(mx[nt], fmaxf(fmaxf(s[0], s[1]), fmaxf(s[2], s[3])));
        }
    }
    #pragma unroll
    for (int nt = 0; nt < 2; ++nt) {
        mx[nt] = fmaxf(mx[nt], __shfl_xor(mx[nt], 16));
        mx[nt] = fmaxf(mx[nt], __shfl_xor(mx[nt], 32));
        if (lane < 16) wred[wid][nt * 16 + lane] = mx[nt];
    }
    __syncthreads();
    float rm[2];
    #pragma unroll
    for (int nt = 0; nt < 2; ++nt) {
        const int c = nt * 16 + (lane & 15);
        rm[nt] = fmaxf(fmaxf(wred[0][c], wred[1][c]), fmaxf(wred[2][c], wred[3][c]));
    }
    __syncthreads();

    float sm[2] = {0.f, 0.f};
    for (int mi = 0; mi < 16; ++mi) {
        const bf16x8_t kf = *(const bf16x8_t*)(kbase + (m0w + mi * 16 + (lane & 15)) * 64 + koff);
        #pragma unroll
        for (int nt = 0; nt < 2; ++nt) {
            f32x4_t s = (f32x4_t){0.f,0.f,0.f,0.f};
            s = __builtin_amdgcn_mfma_f32_16x16x32_bf16(kf, qf[nt], s, 0, 0, 0);
            const float p0 = __expf(s[0] - rm[nt]);
            const float p1 = __expf(s[1] - rm[nt]);
            const float p2 = __expf(s[2] - rm[nt]);
            const float p3 = __expf(s[3] - rm[nt]);
            sm[nt] += (p0 + p1) + (p2 + p3);
            uint2 u;
            u.x = (unsigned int)f2bu(p0) | ((unsigned int)f2bu(p1) << 16);
            u.y = (unsigned int)f2bu(p2) | ((unsigned int)f2bu(p3) << 16);
            const int n = n0 + nt * 16 + (lane & 15);
            const int m = m0w + mi * 16 + ((lane >> 4) << 2);
            *(uint2*)(P + (size_t)((b << 10) + n) * 1024 + m) = u;
        }
    }
    #pragma unroll
    for (int nt = 0; nt < 2; ++nt) {
        sm[nt] += __shfl_xor(sm[nt], 16);
        sm[nt] += __shfl_xor(sm[nt], 32);
        if (lane < 16) wred[wid][nt * 16 + lane] = sm[nt];
    }
    __syncthreads();
    if (tid < 32) {
        const float total = wred[0][tid] + wred[1][tid] + wred[2][tid] + wred[3][tid];
        invs[(b << 10) + n0 + tid] = 1.f / total;
    }
}

// PV + residual: 128x128 tile, 512 thr, K=1024 (16 steps)
__global__ __launch_bounds__(512, 1) void pv_mfma_k(
    const bf16* __restrict__ Vb, const bf16* __restrict__ P,
    const float* __restrict__ invs, const bf16* __restrict__ Yt,
    const float* __restrict__ gamma, float* __restrict__ out)
{
    __shared__ bf16 Als[3][128 * 64];
    __shared__ bf16 Bls[3][128 * 64];
    const int tid = threadIdx.x;
    const int wid = tid >> 6, lane = tid & 63;
    const int wm = wid >> 2, wn = wid & 3;
    const int blk = blockIdx.x;
    const int xc = blk & 7, tt = blk >> 3;
    const int b = xc + ((tt >> 4) << 3);
    const int tile = tt & 15, ct = tile >> 3, nt = tile & 7;
    const int c0 = ct << 7, n0 = nt << 7;

    const int lrow = tid >> 3;
    const int sL8 = (((tid & 7) ^ (lrow & 7)) << 3);
    const bf16* agp[2]; const bf16* bgp[2];
    #pragma unroll
    for (int i = 0; i < 2; ++i) {
        const int r = (i << 6) + lrow;
        agp[i] = Vb + (size_t)((b << 8) + c0 + r) * 1024 + sL8;
        bgp[i] = P + (size_t)((b << 10) + n0 + r) * 1024 + sL8;
    }
    const int rsel = lane & 15;
    const int s0 = (((lane >> 4) ^ (lane & 7)) << 3);
    const int s1 = ((((lane >> 4) + 4) ^ (lane & 7)) << 3);
    const int abase = ((wm << 6) + rsel) << 6;
    const int bbase = ((wn << 5) + rsel) << 6;

    f32x4_t acc[4][2];
    #pragma unroll
    for (int mi = 0; mi < 4; ++mi)
        #pragma unroll
        for (int ni = 0; ni < 2; ++ni)
            acc[mi][ni] = (f32x4_t){0.f,0.f,0.f,0.f};

    auto STAGE = [&](int kt2, int buf) {
        const int koff = kt2 << 6;
        #pragma unroll
        for (int i = 0; i < 2; ++i) {
            gload16(agp[i] + koff, &Als[buf][((i << 6) + (wid << 3)) << 6]);
            gload16(bgp[i] + koff, &Bls[buf][((i << 6) + (wid << 3)) << 6]);
        }
    };

    STAGE(0, 0); STAGE(1, 1);
    for (int kt = 0; kt < 16; ++kt) {
        if (kt < 15) asm volatile("s_waitcnt vmcnt(4)" ::: "memory");
        else         asm volatile("s_waitcnt vmcnt(0)" ::: "memory");
        __builtin_amdgcn_s_barrier();
        asm volatile("" ::: "memory");
        const int cur = kt % 3;
        #pragma unroll
        for (int kh = 0; kh < 2; ++kh) {
            const int sk = kh ? s1 : s0;
            bf16x8_t av[4], bv[2];
            #pragma unroll
            for (int mi = 0; mi < 4; ++mi)
                av[mi] = *(const bf16x8_t*)(&Als[cur][abase + (mi << 10) + sk]);
            #pragma unroll
            for (int ni = 0; ni < 2; ++ni)
                bv[ni] = *(const bf16x8_t*)(&Bls[cur][bbase + (ni << 10) + sk]);
            #pragma unroll
            for (int mi = 0; mi < 4; ++mi)
                #pragma unroll
                for (int ni = 0; ni < 2; ++ni)
                    acc[mi][ni] = __builtin_amdgcn_mfma_f32_16x16x32_bf16(
                        av[mi], bv[ni], acc[mi][ni], 0, 0, 0);
        }
        if (kt + 2 < 16) STAGE(kt + 2, (kt + 2) % 3);
    }

    const float g = gamma[0];
    const int cr = (lane >> 4) << 2, cc = lane & 15;
    #pragma unroll
    for (int ni = 0; ni < 2; ++ni) {
        const int n = n0 + (wn << 5) + (ni << 4) + cc;
        const float gi = g * invs[(b << 10) + n];
        #pragma unroll
        for (int mi = 0; mi < 4; ++mi) {
            const int c = c0 + (wm << 6) + (mi << 4) + cr;
            const bf16* yp = Yt + (size_t)((b << 10) + n) * 256 + c;
            #pragma unroll
            for (int j = 0; j < 4; ++j)
                out[(size_t)((b << 8) + c + j) * 1024 + n] = gi * acc[mi][ni][j] + b2f(yp[j]);
        }
    }
}

// ---------------------------------------------------------------------------
// Workspace (base = ws+32K; round-11 layout)
// ---------------------------------------------------------------------------
extern "C" void kernel_launch(void* const* d_in, const int* in_sizes, int n_in,
                              void* d_out, int out_size, void* d_ws, size_t ws_size,
                              hipStream_t stream)
{
    const float* x     = (const float*)d_in[0];
    const float* t     = (const float*)d_in[1];
    const float* w_t1  = (const float*)d_in[2];
    const float* b_t1  = (const float*)d_in[3];
    const float* w_t2  = (const float*)d_in[4];
    const float* b_t2  = (const float*)d_in[5];
    const float* w_c1  = (const float*)d_in[6];
    const float* b_c1  = (const float*)d_in[7];
    const float* w_c2  = (const float*)d_in[8];
    const float* b_c2  = (const float*)d_in[9];
    const float* w_tr  = (const float*)d_in[10];
    const float* b_tr  = (const float*)d_in[11];
    const float* bn1g  = (const float*)d_in[12];
    const float* bn1b  = (const float*)d_in[13];
    const float* bn2g  = (const float*)d_in[14];
    const float* bn2b  = (const float*)d_in[15];
    const float* wq    = (const float*)d_in[16];
    const float* bq    = (const float*)d_in[17];
    const float* wk    = (const float*)d_in[18];
    const float* bk    = (const float*)d_in[19];
    const float* wv    = (const float*)d_in[20];
    const float* bv    = (const float*)d_in[21];
    const float* gamma = (const float*)d_in[22];
    float* out = (float*)d_out;

    char* ws = (char*)d_ws;
    float* te    = (float*)(ws + 0);
    float* sums1 = (float*)(ws + 16384);
    float* sums2 = (float*)(ws + 18432);
    char* base = ws + 32768;
    bf16* W3_1 = (bf16*)(base);
    bf16* W3_2 = (bf16*)(base + 1179648);
    bf16* W3_3 = (bf16*)(base + 2359296);
    bf16* Xp0  = (bf16*)(base + 3538944);
    bf16* Xp1  = (bf16*)(base + 13008896);
    bf16* Craw = (bf16*)(base + 22478848);
    bf16* P    = (bf16*)(base);                    // 32 MB alias (dead conv bufs)
    bf16* Yt   = (bf16*)(base + 33554432);
    bf16* QKb  = (bf16*)(base + 41943040);
    bf16* Vb   = (bf16*)(base + 44040192);
    float* invs= (float*)(base + 52428800);
    bf16* WQK  = (bf16*)(base + 52494336);
    bf16* WVb  = (bf16*)(base + 52527104);

    prep_all_k<<<3184, 256, 0, stream>>>(
        x, Xp0, Xp1, sums1,
        t, w_t1, b_t1, w_t2, b_t2, te,
        w_c1, w_c2, w_tr, W3_1, W3_2, W3_3,
        wq, wk, wv, WQK, WVb);

    conv_mfma_k<true, true><<<256, 512, 0, stream>>>(Xp0, W3_1, b_c1, Craw, sums1);
    bn_apply_T_k<true><<<2048, 256, 0, stream>>>(Craw, sums1, bn1g, bn1b, te, Xp1);

    conv_mfma_k<true, true><<<256, 512, 0, stream>>>(Xp1, W3_2, b_c2, Craw, sums2);
    bn_apply_T_k<false><<<2048, 256, 0, stream>>>(Craw, sums2, bn2g, bn2b, nullptr, Xp0);

    conv_mfma_k<false, false><<<256, 512, 0, stream>>>(Xp0, W3_3, b_tr, Yt, nullptr);

    qkv_mfma_k<<<384, 512, 0, stream>>>(WVb, Yt, bv, Vb, WQK, bq, bk, QKb);
    softmax_k<<<512, 256, 0, stream>>>(QKb, P, invs);
    pv_mfma_k<<<256, 512, 0, stream>>>(Vb, P, invs, Yt, gamma, out);
}